// Round 11
// baseline (378.086 us; speedup 1.0000x reference)
//
#include <hip/hip_runtime.h>
#include <hip/hip_bf16.h>
#include <stdint.h>

#define NA 131072
#define HD 256
#define NF 4096
#define MINFRAG 3
#define LN_EPS 1e-5f
#define NEPS 1e-12f

// ---- workspace layout (bytes) ----
// zeroed region [0, ZERO_BYTES) via k_zero kernel
#define OFF_CNT    0ull          // NF i32
#define OFF_VSUM   16384ull      // NF f32
#define OFF_VFSUM  32768ull      // NF f32
#define OFF_NVSUM  49152ull      // NF f32
#define OFF_FILL   65536ull      // NF i32
#define OFF_DBL    81920ull      // 261 doubles (ends 84008)
#define OFF_SSUM   86016ull      // NF*HD f32 = 4194304
#define OFF_NSUM   4280320ull    // NF*HD f32 = 4194304
#define ZERO_BYTES 8474624ull    // = 529664 float4
// non-zeroed
#define OFF_OFFS   8474624ull    // NF i32
#define OFF_SVEC   8491008ull    // HD f32
#define OFF_C0     8492032ull    // HD f32
#define OFF_W0     8493056ull    // 1 f32
#define OFF_GBF    8493568ull    // HD*HD bf16 = 131072
#define OFF_ORDER  8624640ull    // NA i32 = 524288
// total: 9,148,928 bytes

#define IDX_TRACE 257
#define IDX_DEVS  258
#define IDX_DEVV  259
#define IDX_VCNT  260

typedef __attribute__((ext_vector_type(8))) short short8;
typedef __attribute__((ext_vector_type(4))) float f32x4;
union F4S8 { float4 f; short8 s; };
union BFU { __hip_bfloat16 b; unsigned short u; };

__device__ __forceinline__ unsigned short f2b(float x) {
    BFU t; t.b = __float2bfloat16(x); return t.u;
}
__device__ __forceinline__ float b2f(unsigned short u) {
    return __uint_as_float(((uint32_t)u) << 16);
}
// fast silu: native v_exp + v_rcp (rel err ~1e-7, error budget ~1e-2)
__device__ __forceinline__ float silu_f(float x) {
    return x * __builtin_amdgcn_rcpf(1.f + __expf(-x));
}

// ---------------- zero workspace head (replaces graph memset) --------------
__global__ __launch_bounds__(256) void k_zero(float4* __restrict__ z) {
    int i = blockIdx.x * 256 + threadIdx.x;   // 2069*256 == 529664 exactly
    float4 v = {0.f, 0.f, 0.f, 0.f};
    z[i] = v;
}

// ---------------- prep: Gbf[o][h], svec, c0, w0 ----------------
__global__ __launch_bounds__(256) void k_prep(
    const float* __restrict__ W1, const float* __restrict__ gamma,
    const float* __restrict__ beta, const float* __restrict__ b1,
    const float* __restrict__ Wv,
    unsigned short* __restrict__ Gbf, float* __restrict__ svec,
    float* __restrict__ c0, float* __restrict__ w0) {
    __shared__ float red[8];
    int o = blockIdx.x;
    int t = threadIdx.x;  // == h
    if (o < HD) {
        float w = W1[(size_t)o * HD + t];
        unsigned short gb = f2b(w * gamma[t]);
        Gbf[(size_t)o * HD + t] = gb;
        float sp = b2f(gb);
        float cp = w * beta[t];
#pragma unroll
        for (int m = 32; m; m >>= 1) { sp += __shfl_xor(sp, m, 64); cp += __shfl_xor(cp, m, 64); }
        int wv = t >> 6;
        if ((t & 63) == 0) { red[wv] = sp; red[4 + wv] = cp; }
        __syncthreads();
        if (t == 0) {
            svec[o] = red[0] + red[1] + red[2] + red[3];
            c0[o]   = red[4] + red[5] + red[6] + red[7] + b1[o];
        }
    } else {
        float v = Wv[t];
#pragma unroll
        for (int m = 32; m; m >>= 1) v += __shfl_xor(v, m, 64);
        int wv = t >> 6;
        if ((t & 63) == 0) red[wv] = v;
        __syncthreads();
        if (t == 0) w0[0] = red[0] + red[1] + red[2] + red[3];
    }
}

// ---------------- stats: contiguous pattern, 2-atom ILP, FULL occupancy ----
__global__ __launch_bounds__(256) void k_stats(
    const float* __restrict__ vs, const int* __restrict__ fid,
    const float* __restrict__ w0p,
    int* __restrict__ cnt, float* __restrict__ vsum,
    float* __restrict__ vfsum, float* __restrict__ nvsum) {
    int gwave = (blockIdx.x * blockDim.x + threadIdx.x) >> 6;
    int lane = threadIdx.x & 63;
    int nw = (gridDim.x * blockDim.x) >> 6;
    float w0 = w0p[0];
    for (int i0 = gwave * 2; i0 < NA; i0 += nw * 2) {
        const float* ba = vs + (size_t)i0 * 3 * HD;
        const float* bb = vs + (size_t)(i0 + 1) * 3 * HD;
        float4 a0 = ((const float4*)(ba))[lane];
        float4 a1 = ((const float4*)(ba + HD))[lane];
        float4 a2 = ((const float4*)(ba + 2 * HD))[lane];
        float4 b0 = ((const float4*)(bb))[lane];
        float4 b1 = ((const float4*)(bb + HD))[lane];
        float4 b2 = ((const float4*)(bb + 2 * HD))[lane];
        float qa0 = a0.x * a0.x + a0.y * a0.y + a0.z * a0.z + a0.w * a0.w;
        float qa1 = a1.x * a1.x + a1.y * a1.y + a1.z * a1.z + a1.w * a1.w;
        float qa2 = a2.x * a2.x + a2.y * a2.y + a2.z * a2.z + a2.w * a2.w;
        float qb0 = b0.x * b0.x + b0.y * b0.y + b0.z * b0.z + b0.w * b0.w;
        float qb1 = b1.x * b1.x + b1.y * b1.y + b1.z * b1.z + b1.w * b1.w;
        float qb2 = b2.x * b2.x + b2.y * b2.y + b2.z * b2.z + b2.w * b2.w;
#pragma unroll
        for (int m = 32; m; m >>= 1) {   // six independent chains, interleaved
            qa0 += __shfl_xor(qa0, m, 64);
            qa1 += __shfl_xor(qa1, m, 64);
            qa2 += __shfl_xor(qa2, m, 64);
            qb0 += __shfl_xor(qb0, m, 64);
            qb1 += __shfl_xor(qb1, m, 64);
            qb2 += __shfl_xor(qb2, m, 64);
        }
        if (lane == 0) {
            float vma = (sqrtf(qa0) + sqrtf(qa1) + sqrtf(qa2)) * (1.f / 3.f);
            float vmb = (sqrtf(qb0) + sqrtf(qb1) + sqrtf(qb2)) * (1.f / 3.f);
            float vfa = silu_f(vma * w0);
            float vfb = silu_f(vmb * w0);
            float nva = vfa / fmaxf(fabsf(vfa), NEPS);
            float nvb = vfb / fmaxf(fabsf(vfb), NEPS);
            int fa = fid[i0], fb = fid[i0 + 1];
            atomicAdd(&cnt[fa], 1);
            atomicAdd(&vsum[fa], vma);
            atomicAdd(&vfsum[fa], vfa);
            atomicAdd(&nvsum[fa], nva);
            atomicAdd(&cnt[fb], 1);
            atomicAdd(&vsum[fb], vmb);
            atomicAdd(&vfsum[fb], vfb);
            atomicAdd(&nvsum[fb], nvb);
        }
    }
}

// ---------------- scan ----------------
__global__ __launch_bounds__(256) void k_scan(const int* __restrict__ cnt,
                                              int* __restrict__ offs) {
    __shared__ int wsum[4];
    int t = threadIdx.x;
    int base = t * 16;
    int c[16];
    int tot = 0;
#pragma unroll
    for (int j = 0; j < 16; ++j) { c[j] = cnt[base + j]; tot += c[j]; }
    int lane = t & 63, w = t >> 6;
    int v = tot;
#pragma unroll
    for (int d = 1; d < 64; d <<= 1) {
        int o = __shfl_up(v, d, 64);
        if (lane >= d) v += o;
    }
    if (lane == 63) wsum[w] = v;
    __syncthreads();
    int wbase = 0;
    for (int i = 0; i < w; ++i) wbase += wsum[i];
    int run = wbase + v - tot;
#pragma unroll
    for (int j = 0; j < 16; ++j) { offs[base + j] = run; run += c[j]; }
}

// ---------------- scatter ----------------
__global__ __launch_bounds__(256) void k_scatter(
    const int* __restrict__ fid, const int* __restrict__ offs,
    int* __restrict__ fill, int* __restrict__ order) {
    int i = blockIdx.x * blockDim.x + threadIdx.x;
    if (i < NA) {
        int f = fid[i];
        int p = atomicAdd(&fill[f], 1);
        order[offs[f] + p] = i;
    }
}

// ---- GEMM: single A-tile stage, B from L2, segment-mask epilogue ----
__global__ __launch_bounds__(256) void k_gemm(
    const float* __restrict__ A, const unsigned short* __restrict__ Gbf,
    const float* __restrict__ svec, const float* __restrict__ c0,
    const int* __restrict__ order, const int* __restrict__ fid,
    const int* __restrict__ offs, const int* __restrict__ cnt,
    float* __restrict__ ssum, float* __restrict__ nsum) {
    __shared__ float4 As16[64 * 32];    // 32 KB: full A tile bf16, xor-swizzled
    __shared__ float muS[64], rsS[64], rnS[64];
    __shared__ float sqL[64][4];
    __shared__ int ridS[64], fragS[64];
    __shared__ unsigned long long segMaskS;

    int tid = threadIdx.x;
    int lane = tid & 63, wid = tid >> 6;
    int r0 = blockIdx.x * 64;
    int rowT = tid >> 4;   // 0..15
    int c4 = tid & 15;

    if (tid < 64) {
        int gi = order[r0 + tid];
        ridS[tid] = gi;
        fragS[tid] = fid[gi];
    }
    __syncthreads();
    // segment-boundary mask (wave 0 covers rows 0..63)
    if (wid == 0) {
        int f = fragS[lane];
        int fp = (lane == 0) ? -1 : fragS[lane - 1];
        unsigned long long m = __ballot(f != fp);
        if (lane == 0) segMaskS = m | 1ull;
    }
    int rid[4];
#pragma unroll
    for (int p = 0; p < 4; ++p) rid[p] = ridS[16 * p + rowT];

    // ---- stage the WHOLE A tile: 16 loads/thread, one latency exposure ----
    float s1p[4] = {0, 0, 0, 0}, s2p[4] = {0, 0, 0, 0};
#pragma unroll
    for (int kc = 0; kc < 4; ++kc)
#pragma unroll
        for (int p = 0; p < 4; ++p) {
            int row = 16 * p + rowT;
            float4 v = *(const float4*)(A + (size_t)rid[p] * HD + kc * 64 + c4 * 4);
            s1p[p] += v.x + v.y + v.z + v.w;
            s2p[p] += v.x * v.x + v.y * v.y + v.z * v.z + v.w * v.w;
            ushort4 pk;
            pk.x = f2b(v.x); pk.y = f2b(v.y); pk.z = f2b(v.z); pk.w = f2b(v.w);
            int slot = row * 32 + kc * 8 + ((c4 >> 1) ^ (row & 7));
            ((ushort4*)&As16[slot])[c4 & 1] = pk;
        }
    // LN row stats (16-lane groups)
#pragma unroll
    for (int p = 0; p < 4; ++p) {
        float s1 = s1p[p], s2 = s2p[p];
#pragma unroll
        for (int m = 1; m < 16; m <<= 1) {
            s1 += __shfl_xor(s1, m, 64);
            s2 += __shfl_xor(s2, m, 64);
        }
        if (c4 == 0) {
            int row = 16 * p + rowT;
            float mu_ = s1 * (1.f / HD);
            float var = s2 * (1.f / HD) - mu_ * mu_;
            muS[row] = mu_;
            rsS[row] = rsqrtf(var + LN_EPS);
        }
    }
    __syncthreads();   // A tile + muS + segMaskS ready

    // ---- MFMA phase: B fragments straight from L2-resident Gbf ----
    int lg = lane >> 4;
    const unsigned short* bp[4];
#pragma unroll
    for (int ni = 0; ni < 4; ++ni)
        bp[ni] = Gbf + (size_t)(wid * 64 + ni * 16 + (lane & 15)) * HD + lg * 8;

    f32x4 acc[4][4] = {};
#pragma unroll
    for (int kc = 0; kc < 4; ++kc) {
        short8 bfr[2][4];
#pragma unroll
        for (int kk = 0; kk < 2; ++kk)
#pragma unroll
            for (int ni = 0; ni < 4; ++ni)
                bfr[kk][ni] = *(const short8*)(bp[ni] + kc * 64 + kk * 32);
#pragma unroll
        for (int kk = 0; kk < 2; ++kk) {
            int jp = kk * 4 + lg;
            short8 a[4];
#pragma unroll
            for (int mi = 0; mi < 4; ++mi) {
                int r = mi * 16 + (lane & 15);
                F4S8 t_; t_.f = As16[r * 32 + kc * 8 + (jp ^ (r & 7))];
                a[mi] = t_.s;
            }
#pragma unroll
            for (int mi = 0; mi < 4; ++mi)
#pragma unroll
                for (int ni = 0; ni < 4; ++ni)
                    acc[mi][ni] = __builtin_amdgcn_mfma_f32_16x16x32_bf16(
                        a[mi], bfr[kk][ni], acc[mi][ni], 0, 0, 0);
        }
    }
    __syncthreads();   // all waves done reading As16 -> safe to reuse as feat

    float sv[4], cv[4];
#pragma unroll
    for (int ni = 0; ni < 4; ++ni) {
        int c = wid * 64 + ni * 16 + (lane & 15);
        sv[ni] = svec[c];
        cv[ni] = c0[c];
    }
    // epilogue: affine + silu -> feat tile in LDS (reuses As16) + per-row sq
    unsigned short* featS = (unsigned short*)As16;
    float sq[4][4];
#pragma unroll
    for (int mi = 0; mi < 4; ++mi)
#pragma unroll
        for (int q = 0; q < 4; ++q) {
            int rl = mi * 16 + (lane >> 4) * 4 + q;
            float mu_ = muS[rl], rs_ = rsS[rl];
            float sqa = 0.f;
#pragma unroll
            for (int ni = 0; ni < 4; ++ni) {
                int c = wid * 64 + ni * 16 + (lane & 15);
                float pre = rs_ * (acc[mi][ni][q] - mu_ * sv[ni]) + cv[ni];
                unsigned short us = f2b(silu_f(pre));
                featS[rl * 256 + (c ^ ((rl & 7) << 2))] = us;
                float fr = b2f(us);
                sqa += fr * fr;
            }
            sq[mi][q] = sqa;
        }
#pragma unroll
    for (int mi = 0; mi < 4; ++mi)
#pragma unroll
        for (int q = 0; q < 4; ++q) {
            float s_ = sq[mi][q];
            s_ += __shfl_xor(s_, 1, 64);
            s_ += __shfl_xor(s_, 2, 64);
            s_ += __shfl_xor(s_, 4, 64);
            s_ += __shfl_xor(s_, 8, 64);
            if ((lane & 15) == 0) sqL[mi * 16 + (lane >> 4) * 4 + q][wid] = s_;
        }
    __syncthreads();
    if (tid < 64) {
        float t = sqL[tid][0] + sqL[tid][1] + sqL[tid][2] + sqL[tid][3];
        rnS[tid] = 1.f / fmaxf(sqrtf(t), NEPS);
    }
    __syncthreads();
    // fragment-segment accumulation: branch-free per-segment inner loops
    int cc = wid * 64 + lane;
    unsigned long long mm = segMaskS >> 1;   // bit j => segment starts at row j+1
    int pos = 0;
    while (pos < 64) {
        int len = mm ? __ffsll((long long)mm) : (64 - pos);
        if (len > 64 - pos) len = 64 - pos;
        int rend = pos + len;
        float sA = 0.f, nA = 0.f;
        int r = pos;
        for (; r + 3 < rend; r += 4) {
            float v0 = b2f(featS[(r + 0) * 256 + (cc ^ (((r + 0) & 7) << 2))]);
            float v1 = b2f(featS[(r + 1) * 256 + (cc ^ (((r + 1) & 7) << 2))]);
            float v2 = b2f(featS[(r + 2) * 256 + (cc ^ (((r + 2) & 7) << 2))]);
            float v3 = b2f(featS[(r + 3) * 256 + (cc ^ (((r + 3) & 7) << 2))]);
            sA += (v0 + v1) + (v2 + v3);
            nA = fmaf(v0, rnS[r + 0], nA);
            nA = fmaf(v1, rnS[r + 1], nA);
            nA = fmaf(v2, rnS[r + 2], nA);
            nA = fmaf(v3, rnS[r + 3], nA);
        }
        for (; r < rend; ++r) {
            float v = b2f(featS[r * 256 + (cc ^ ((r & 7) << 2))]);
            sA += v;
            nA = fmaf(v, rnS[r], nA);
        }
        int curF = fragS[pos];
        int gs = offs[curF], n = cnt[curF];
        if (gs >= r0 && gs + n <= r0 + 64) {
            ssum[(size_t)curF * HD + cc] = sA;
            nsum[(size_t)curF * HD + cc] = nA;
        } else {
            atomicAdd(&ssum[(size_t)curF * HD + cc], sA);
            atomicAdd(&nsum[(size_t)curF * HD + cc], nA);
        }
        mm >>= len;
        pos = rend;
    }
}

// ---------------- fragment pass ----------------
__global__ __launch_bounds__(256) void k_frag(
    const float* __restrict__ ssum, const float* __restrict__ nsum,
    const int* __restrict__ cnt, const float* __restrict__ vsum,
    const float* __restrict__ vfsum, const float* __restrict__ nvsum,
    double* __restrict__ dbl) {
    int gwave = (blockIdx.x * blockDim.x + threadIdx.x) >> 6;
    int lane = threadIdx.x & 63;
    int nw = (gridDim.x * blockDim.x) >> 6;

    double la0 = 0, la1 = 0, la2 = 0, la3 = 0;
    double lv = 0, ltr = 0, lvc = 0, ldS = 0, ldV = 0;

    for (int f = gwave; f < NF; f += nw) {
        float4 s = ((const float4*)(ssum + (size_t)f * HD))[lane];
        float4 nn = ((const float4*)(nsum + (size_t)f * HD))[lane];
        int c = cnt[f];
        float ssq = s.x * s.x + s.y * s.y + s.z * s.z + s.w * s.w;
        float dsn = nn.x * s.x + nn.y * s.y + nn.z * s.z + nn.w * s.w;
#pragma unroll
        for (int m = 32; m; m >>= 1) {
            ssq += __shfl_xor(ssq, m, 64);
            dsn += __shfl_xor(dsn, m, 64);
        }
        float inv_all = 1.f / fmaxf((float)c, 1.f);
        float m0 = s.x * inv_all, m1 = s.y * inv_all, m2 = s.z * inv_all, m3 = s.w * inv_all;
        float ssq_mean = ssq * inv_all * inv_all;
        float vfr = vsum[f] * inv_all;
        float nrm2 = ssq_mean + vfr * vfr;
        float inv = 1.f / fmaxf(sqrtf(nrm2), NEPS);
        la0 += (double)(m0 * inv);
        la1 += (double)(m1 * inv);
        la2 += (double)(m2 * inv);
        la3 += (double)(m3 * inv);
        if (lane == 0) {
            lv += (double)(vfr * inv);
            ltr += (double)(nrm2 * inv * inv);
            if (c >= MINFRAG) {
                lvc += (double)c;
                float denom = fmaxf(sqrtf(ssq), NEPS);
                ldS += (double)c - (double)(dsn / denom);
                float vfm = vfsum[f] * inv_all;
                float vsgn = vfm / fmaxf(fabsf(vfm), NEPS);
                ldV += (double)c - (double)(vsgn * nvsum[f]);
            }
        }
    }
    atomicAdd(&dbl[4 * lane + 0], la0);
    atomicAdd(&dbl[4 * lane + 1], la1);
    atomicAdd(&dbl[4 * lane + 2], la2);
    atomicAdd(&dbl[4 * lane + 3], la3);
    if (lane == 0) {
        atomicAdd(&dbl[256], lv);
        atomicAdd(&dbl[IDX_TRACE], ltr);
        atomicAdd(&dbl[IDX_VCNT], lvc);
        atomicAdd(&dbl[IDX_DEVS], ldS);
        atomicAdd(&dbl[IDX_DEVV], ldV);
    }
}

// ---------------- final combine ----------------
__global__ __launch_bounds__(64) void k_final(const double* __restrict__ dbl,
                                              float* __restrict__ out) {
    if (threadIdx.x == 0 && blockIdx.x == 0) {
        double s2 = 0;
        for (int d = 0; d < 257; ++d) s2 += dbl[d] * dbl[d];
        double off = s2 - dbl[IDX_TRACE];
        double inter = off / ((double)NF * NF - NF + 1e-6);
        double vc = fmax(dbl[IDX_VCNT], 1.0);
        double total = dbl[IDX_DEVS] / vc + dbl[IDX_DEVV] / vc + 0.2 * inter;
        out[0] = (float)(0.03 * 0.05 * total);
    }
}

extern "C" void kernel_launch(void* const* d_in, const int* in_sizes, int n_in,
                              void* d_out, int out_size, void* d_ws, size_t ws_size,
                              hipStream_t stream) {
    const float* scalar_short = (const float*)d_in[0];
    const float* vector_short = (const float*)d_in[2];
    const int* fragment_ids = (const int*)d_in[4];
    const float* ln_gamma = (const float*)d_in[5];
    const float* ln_beta = (const float*)d_in[6];
    const float* W1 = (const float*)d_in[7];
    const float* b1 = (const float*)d_in[8];
    const float* Wv = (const float*)d_in[9];
    float* out = (float*)d_out;

    char* ws = (char*)d_ws;
    int* cnt = (int*)(ws + OFF_CNT);
    float* vsum = (float*)(ws + OFF_VSUM);
    float* vfsum = (float*)(ws + OFF_VFSUM);
    float* nvsum = (float*)(ws + OFF_NVSUM);
    int* fill = (int*)(ws + OFF_FILL);
    double* dbl = (double*)(ws + OFF_DBL);
    float* ssum = (float*)(ws + OFF_SSUM);
    float* nsum = (float*)(ws + OFF_NSUM);
    int* offs = (int*)(ws + OFF_OFFS);
    float* svec = (float*)(ws + OFF_SVEC);
    float* c0 = (float*)(ws + OFF_C0);
    float* w0 = (float*)(ws + OFF_W0);
    unsigned short* Gbf = (unsigned short*)(ws + OFF_GBF);
    int* order = (int*)(ws + OFF_ORDER);

    k_zero<<<2069, 256, 0, stream>>>((float4*)ws);   // [0, 8474624) exactly
    k_prep<<<HD + 1, 256, 0, stream>>>(W1, ln_gamma, ln_beta, b1, Wv, Gbf, svec, c0, w0);
    k_stats<<<8192, 256, 0, stream>>>(vector_short, fragment_ids, w0, cnt, vsum, vfsum, nvsum);
    k_scan<<<1, 256, 0, stream>>>(cnt, offs);
    k_scatter<<<NA / 256, 256, 0, stream>>>(fragment_ids, offs, fill, order);
    k_gemm<<<NA / 64, 256, 0, stream>>>(scalar_short, Gbf, svec, c0, order,
                                        fragment_ids, offs, cnt, ssum, nsum);
    k_frag<<<512, 256, 0, stream>>>(ssum, nsum, cnt, vsum, vfsum, nvsum, dbl);
    k_final<<<1, 64, 0, stream>>>(dbl, out);
}

// Round 13
// 275.285 us; speedup vs baseline: 1.3734x; 1.3734x over previous
//
#include <hip/hip_runtime.h>
#include <hip/hip_bf16.h>
#include <stdint.h>

#define NA 131072
#define HD 256
#define NF 4096
#define MINFRAG 3
#define LN_EPS 1e-5f
#define NEPS 1e-12f

// ---- workspace layout (bytes) ----
// zeroed region [0, ZERO_BYTES) via k_zero kernel
#define OFF_CNT    0ull          // NF i32
#define OFF_VSUM   16384ull      // NF f32
#define OFF_VFSUM  32768ull      // NF f32
#define OFF_NVSUM  49152ull      // NF f32
#define OFF_FILL   65536ull      // NF i32
#define OFF_DBL    81920ull      // 261 doubles (ends 84008)
#define OFF_SSUM   86016ull      // NF*HD f32 = 4194304
#define OFF_NSUM   4280320ull    // NF*HD f32 = 4194304
#define ZERO_BYTES 8474624ull    // = 529664 float4 = 2069*256
// non-zeroed
#define OFF_OFFS   8474624ull    // NF i32
#define OFF_SVEC   8491008ull    // HD f32
#define OFF_C0     8492032ull    // HD f32
#define OFF_W0     8493056ull    // 1 f32
#define OFF_GBF    8493568ull    // HD*HD bf16 = 131072
#define OFF_ORDER  8624640ull    // NA i32 = 524288
// total: 9,148,928 bytes

#define IDX_TRACE 257
#define IDX_DEVS  258
#define IDX_DEVV  259
#define IDX_VCNT  260

typedef __attribute__((ext_vector_type(8))) short short8;
typedef __attribute__((ext_vector_type(4))) float f32x4;
union F4S8 { float4 f; short8 s; };
union BFU { __hip_bfloat16 b; unsigned short u; };

__device__ __forceinline__ unsigned short f2b(float x) {
    BFU t; t.b = __float2bfloat16(x); return t.u;
}
__device__ __forceinline__ float b2f(unsigned short u) {
    return __uint_as_float(((uint32_t)u) << 16);
}
// fast silu: native v_exp + v_rcp (rel err ~1e-7, error budget ~1e-2)
__device__ __forceinline__ float silu_f(float x) {
    return x * __builtin_amdgcn_rcpf(1.f + __expf(-x));
}

// ---------------- zero workspace head ----------------
__global__ __launch_bounds__(256) void k_zero(float4* __restrict__ z) {
    int i = blockIdx.x * 256 + threadIdx.x;   // 2069*256 == 529664 exactly
    float4 v = {0.f, 0.f, 0.f, 0.f};
    z[i] = v;
}

// ---------------- prep: Gbf[o][h], svec, c0, w0 ----------------
__global__ __launch_bounds__(256) void k_prep(
    const float* __restrict__ W1, const float* __restrict__ gamma,
    const float* __restrict__ beta, const float* __restrict__ b1,
    const float* __restrict__ Wv,
    unsigned short* __restrict__ Gbf, float* __restrict__ svec,
    float* __restrict__ c0, float* __restrict__ w0) {
    __shared__ float red[8];
    int o = blockIdx.x;
    int t = threadIdx.x;  // == h
    if (o < HD) {
        float w = W1[(size_t)o * HD + t];
        unsigned short gb = f2b(w * gamma[t]);
        Gbf[(size_t)o * HD + t] = gb;
        float sp = b2f(gb);
        float cp = w * beta[t];
#pragma unroll
        for (int m = 32; m; m >>= 1) { sp += __shfl_xor(sp, m, 64); cp += __shfl_xor(cp, m, 64); }
        int wv = t >> 6;
        if ((t & 63) == 0) { red[wv] = sp; red[4 + wv] = cp; }
        __syncthreads();
        if (t == 0) {
            svec[o] = red[0] + red[1] + red[2] + red[3];
            c0[o]   = red[4] + red[5] + red[6] + red[7] + b1[o];
        }
    } else {
        float v = Wv[t];
#pragma unroll
        for (int m = 32; m; m >>= 1) v += __shfl_xor(v, m, 64);
        int wv = t >> 6;
        if ((t & 63) == 0) red[wv] = v;
        __syncthreads();
        if (t == 0) w0[0] = red[0] + red[1] + red[2] + red[3];
    }
}

// ---------------- hist: fragment counts only ----------------
__global__ __launch_bounds__(256) void k_hist(
    const int* __restrict__ fid, int* __restrict__ cnt) {
    int i = blockIdx.x * 256 + threadIdx.x;
    if (i < NA) atomicAdd(&cnt[fid[i]], 1);
}

// ---------------- scan ----------------
__global__ __launch_bounds__(256) void k_scan(const int* __restrict__ cnt,
                                              int* __restrict__ offs) {
    __shared__ int wsum[4];
    int t = threadIdx.x;
    int base = t * 16;
    int c[16];
    int tot = 0;
#pragma unroll
    for (int j = 0; j < 16; ++j) { c[j] = cnt[base + j]; tot += c[j]; }
    int lane = t & 63, w = t >> 6;
    int v = tot;
#pragma unroll
    for (int d = 1; d < 64; d <<= 1) {
        int o = __shfl_up(v, d, 64);
        if (lane >= d) v += o;
    }
    if (lane == 63) wsum[w] = v;
    __syncthreads();
    int wbase = 0;
    for (int i = 0; i < w; ++i) wbase += wsum[i];
    int run = wbase + v - tot;
#pragma unroll
    for (int j = 0; j < 16; ++j) { offs[base + j] = run; run += c[j]; }
}

// ---------------- scatter ----------------
__global__ __launch_bounds__(256) void k_scatter(
    const int* __restrict__ fid, const int* __restrict__ offs,
    int* __restrict__ fill, int* __restrict__ order) {
    int i = blockIdx.x * blockDim.x + threadIdx.x;
    if (i < NA) {
        int f = fid[i];
        int p = atomicAdd(&fill[f], 1);
        order[offs[f] + p] = i;
    }
}

// ---- GEMM (R10 body) + fused per-block vec-stats appendix ----
__global__ __launch_bounds__(256) void k_gemm(
    const float* __restrict__ A, const unsigned short* __restrict__ Gbf,
    const float* __restrict__ svec, const float* __restrict__ c0,
    const float* __restrict__ vs, const float* __restrict__ w0p,
    const int* __restrict__ order, const int* __restrict__ fid,
    const int* __restrict__ offs, const int* __restrict__ cnt,
    float* __restrict__ vsum, float* __restrict__ vfsum,
    float* __restrict__ nvsum,
    float* __restrict__ ssum, float* __restrict__ nsum) {
    __shared__ float4 As16[64 * 32];    // 32 KB: full A tile bf16, xor-swizzled
    __shared__ float muS[64], rsS[64], rnS[64];
    __shared__ float sqL[64][4];
    __shared__ int ridS[64], fragS[64];

    int tid = threadIdx.x;
    int lane = tid & 63, wid = tid >> 6;
    int r0 = blockIdx.x * 64;
    int rowT = tid >> 4;   // 0..15
    int c4 = tid & 15;

    if (tid < 64) {
        int gi = order[r0 + tid];
        ridS[tid] = gi;
        fragS[tid] = fid[gi];
    }
    __syncthreads();
    int rid[4];
#pragma unroll
    for (int p = 0; p < 4; ++p) rid[p] = ridS[16 * p + rowT];

    // ---- stage the WHOLE A tile: 16 loads/thread, one latency exposure ----
    float s1p[4] = {0, 0, 0, 0}, s2p[4] = {0, 0, 0, 0};
#pragma unroll
    for (int kc = 0; kc < 4; ++kc)
#pragma unroll
        for (int p = 0; p < 4; ++p) {
            int row = 16 * p + rowT;
            float4 v = *(const float4*)(A + (size_t)rid[p] * HD + kc * 64 + c4 * 4);
            s1p[p] += v.x + v.y + v.z + v.w;
            s2p[p] += v.x * v.x + v.y * v.y + v.z * v.z + v.w * v.w;
            ushort4 pk;
            pk.x = f2b(v.x); pk.y = f2b(v.y); pk.z = f2b(v.z); pk.w = f2b(v.w);
            int slot = row * 32 + kc * 8 + ((c4 >> 1) ^ (row & 7));
            ((ushort4*)&As16[slot])[c4 & 1] = pk;
        }
    // LN row stats (16-lane groups)
#pragma unroll
    for (int p = 0; p < 4; ++p) {
        float s1 = s1p[p], s2 = s2p[p];
#pragma unroll
        for (int m = 1; m < 16; m <<= 1) {
            s1 += __shfl_xor(s1, m, 64);
            s2 += __shfl_xor(s2, m, 64);
        }
        if (c4 == 0) {
            int row = 16 * p + rowT;
            float mu_ = s1 * (1.f / HD);
            float var = s2 * (1.f / HD) - mu_ * mu_;
            muS[row] = mu_;
            rsS[row] = rsqrtf(var + LN_EPS);
        }
    }
    __syncthreads();   // A tile + muS ready

    // ---- MFMA phase: B fragments straight from L2-resident Gbf ----
    int lg = lane >> 4;
    const unsigned short* bp[4];
#pragma unroll
    for (int ni = 0; ni < 4; ++ni)
        bp[ni] = Gbf + (size_t)(wid * 64 + ni * 16 + (lane & 15)) * HD + lg * 8;

    f32x4 acc[4][4] = {};
#pragma unroll
    for (int kc = 0; kc < 4; ++kc) {
        short8 bfr[2][4];
#pragma unroll
        for (int kk = 0; kk < 2; ++kk)
#pragma unroll
            for (int ni = 0; ni < 4; ++ni)
                bfr[kk][ni] = *(const short8*)(bp[ni] + kc * 64 + kk * 32);
#pragma unroll
        for (int kk = 0; kk < 2; ++kk) {
            int jp = kk * 4 + lg;
            short8 a[4];
#pragma unroll
            for (int mi = 0; mi < 4; ++mi) {
                int r = mi * 16 + (lane & 15);
                F4S8 t_; t_.f = As16[r * 32 + kc * 8 + (jp ^ (r & 7))];
                a[mi] = t_.s;
            }
#pragma unroll
            for (int mi = 0; mi < 4; ++mi)
#pragma unroll
                for (int ni = 0; ni < 4; ++ni)
                    acc[mi][ni] = __builtin_amdgcn_mfma_f32_16x16x32_bf16(
                        a[mi], bfr[kk][ni], acc[mi][ni], 0, 0, 0);
        }
    }
    __syncthreads();   // all waves done reading As16 -> safe to reuse as feat

    float sv[4], cv[4];
#pragma unroll
    for (int ni = 0; ni < 4; ++ni) {
        int c = wid * 64 + ni * 16 + (lane & 15);
        sv[ni] = svec[c];
        cv[ni] = c0[c];
    }
    // epilogue: affine + silu -> feat tile in LDS (reuses As16) + per-row sq
    unsigned short* featS = (unsigned short*)As16;
    float sq[4][4];
#pragma unroll
    for (int mi = 0; mi < 4; ++mi)
#pragma unroll
        for (int q = 0; q < 4; ++q) {
            int rl = mi * 16 + (lane >> 4) * 4 + q;
            float mu_ = muS[rl], rs_ = rsS[rl];
            float sqa = 0.f;
#pragma unroll
            for (int ni = 0; ni < 4; ++ni) {
                int c = wid * 64 + ni * 16 + (lane & 15);
                float pre = rs_ * (acc[mi][ni][q] - mu_ * sv[ni]) + cv[ni];
                unsigned short us = f2b(silu_f(pre));
                featS[rl * 256 + (c ^ ((rl & 7) << 2))] = us;
                float fr = b2f(us);
                sqa += fr * fr;
            }
            sq[mi][q] = sqa;
        }
#pragma unroll
    for (int mi = 0; mi < 4; ++mi)
#pragma unroll
        for (int q = 0; q < 4; ++q) {
            float s_ = sq[mi][q];
            s_ += __shfl_xor(s_, 1, 64);
            s_ += __shfl_xor(s_, 2, 64);
            s_ += __shfl_xor(s_, 4, 64);
            s_ += __shfl_xor(s_, 8, 64);
            if ((lane & 15) == 0) sqL[mi * 16 + (lane >> 4) * 4 + q][wid] = s_;
        }
    __syncthreads();
    if (tid < 64) {
        float t = sqL[tid][0] + sqL[tid][1] + sqL[tid][2] + sqL[tid][3];
        rnS[tid] = 1.f / fmaxf(sqrtf(t), NEPS);
    }
    __syncthreads();
    // fragment-segment accumulation: one column per thread, scan 64 rows
    int cc = wid * 64 + lane;
    float sAcc = 0.f, nAcc = 0.f;
    int curF = fragS[0];
    for (int row = 0; row < 64; ++row) {
        int f = fragS[row];
        if (f != curF) {
            int gs = offs[curF], n = cnt[curF];
            if (gs >= r0 && gs + n <= r0 + 64) {
                ssum[(size_t)curF * HD + cc] = sAcc;
                nsum[(size_t)curF * HD + cc] = nAcc;
            } else {
                atomicAdd(&ssum[(size_t)curF * HD + cc], sAcc);
                atomicAdd(&nsum[(size_t)curF * HD + cc], nAcc);
            }
            sAcc = 0.f; nAcc = 0.f; curF = f;
        }
        float v = b2f(featS[row * 256 + (cc ^ ((row & 7) << 2))]);
        sAcc += v;
        nAcc = fmaf(v, rnS[row], nAcc);
    }
    {
        int gs = offs[curF], n = cnt[curF];
        if (gs >= r0 && gs + n <= r0 + 64) {
            ssum[(size_t)curF * HD + cc] = sAcc;
            nsum[(size_t)curF * HD + cc] = nAcc;
        } else {
            atomicAdd(&ssum[(size_t)curF * HD + cc], sAcc);
            atomicAdd(&nsum[(size_t)curF * HD + cc], nAcc);
        }
    }

    // ---- appendix: vec-stats for this block's 64 atoms (barrier-free;
    //      overlaps other blocks' gather/MFMA phases) ----
    {
        float w0 = w0p[0];
#pragma unroll 1
        for (int j = 0; j < 16; j += 2) {
            int lr0 = wid * 16 + j, lr1 = lr0 + 1;
            int gia = ridS[lr0], gib = ridS[lr1];
            const float* ba = vs + (size_t)gia * 3 * HD;
            const float* bb = vs + (size_t)gib * 3 * HD;
            float4 a0 = ((const float4*)(ba))[lane];
            float4 a1 = ((const float4*)(ba + HD))[lane];
            float4 a2 = ((const float4*)(ba + 2 * HD))[lane];
            float4 b0 = ((const float4*)(bb))[lane];
            float4 b1 = ((const float4*)(bb + HD))[lane];
            float4 b2 = ((const float4*)(bb + 2 * HD))[lane];
            float qa0 = a0.x * a0.x + a0.y * a0.y + a0.z * a0.z + a0.w * a0.w;
            float qa1 = a1.x * a1.x + a1.y * a1.y + a1.z * a1.z + a1.w * a1.w;
            float qa2 = a2.x * a2.x + a2.y * a2.y + a2.z * a2.z + a2.w * a2.w;
            float qb0 = b0.x * b0.x + b0.y * b0.y + b0.z * b0.z + b0.w * b0.w;
            float qb1 = b1.x * b1.x + b1.y * b1.y + b1.z * b1.z + b1.w * b1.w;
            float qb2 = b2.x * b2.x + b2.y * b2.y + b2.z * b2.z + b2.w * b2.w;
#pragma unroll
            for (int m = 32; m; m >>= 1) {
                qa0 += __shfl_xor(qa0, m, 64);
                qa1 += __shfl_xor(qa1, m, 64);
                qa2 += __shfl_xor(qa2, m, 64);
                qb0 += __shfl_xor(qb0, m, 64);
                qb1 += __shfl_xor(qb1, m, 64);
                qb2 += __shfl_xor(qb2, m, 64);
            }
            if (lane == 0) {
                float vma = (sqrtf(qa0) + sqrtf(qa1) + sqrtf(qa2)) * (1.f / 3.f);
                float vmb = (sqrtf(qb0) + sqrtf(qb1) + sqrtf(qb2)) * (1.f / 3.f);
                float vfa = silu_f(vma * w0);
                float vfb = silu_f(vmb * w0);
                float nva = vfa / fmaxf(fabsf(vfa), NEPS);
                float nvb = vfb / fmaxf(fabsf(vfb), NEPS);
                int fa = fragS[lr0], fb = fragS[lr1];
                atomicAdd(&vsum[fa], vma);
                atomicAdd(&vfsum[fa], vfa);
                atomicAdd(&nvsum[fa], nva);
                atomicAdd(&vsum[fb], vmb);
                atomicAdd(&vfsum[fb], vfb);
                atomicAdd(&nvsum[fb], nvb);
            }
        }
    }
}

// ---------------- fragment pass (R10-exact) ----------------
__global__ __launch_bounds__(256) void k_frag(
    const float* __restrict__ ssum, const float* __restrict__ nsum,
    const int* __restrict__ cnt, const float* __restrict__ vsum,
    const float* __restrict__ vfsum, const float* __restrict__ nvsum,
    double* __restrict__ dbl) {
    int gwave = (blockIdx.x * blockDim.x + threadIdx.x) >> 6;
    int lane = threadIdx.x & 63;
    int nw = (gridDim.x * blockDim.x) >> 6;

    double la0 = 0, la1 = 0, la2 = 0, la3 = 0;
    double lv = 0, ltr = 0, lvc = 0, ldS = 0, ldV = 0;

    for (int f = gwave; f < NF; f += nw) {
        float4 s = ((const float4*)(ssum + (size_t)f * HD))[lane];
        float4 nn = ((const float4*)(nsum + (size_t)f * HD))[lane];
        int c = cnt[f];
        float ssq = s.x * s.x + s.y * s.y + s.z * s.z + s.w * s.w;
        float dsn = nn.x * s.x + nn.y * s.y + nn.z * s.z + nn.w * s.w;
#pragma unroll
        for (int m = 32; m; m >>= 1) {
            ssq += __shfl_xor(ssq, m, 64);
            dsn += __shfl_xor(dsn, m, 64);
        }
        float inv_all = 1.f / fmaxf((float)c, 1.f);
        float m0 = s.x * inv_all, m1 = s.y * inv_all, m2 = s.z * inv_all, m3 = s.w * inv_all;
        float ssq_mean = ssq * inv_all * inv_all;
        float vfr = vsum[f] * inv_all;
        float nrm2 = ssq_mean + vfr * vfr;
        float inv = 1.f / fmaxf(sqrtf(nrm2), NEPS);
        la0 += (double)(m0 * inv);
        la1 += (double)(m1 * inv);
        la2 += (double)(m2 * inv);
        la3 += (double)(m3 * inv);
        if (lane == 0) {
            lv += (double)(vfr * inv);
            ltr += (double)(nrm2 * inv * inv);
            if (c >= MINFRAG) {
                lvc += (double)c;
                float denom = fmaxf(sqrtf(ssq), NEPS);
                ldS += (double)c - (double)(dsn / denom);
                float vfm = vfsum[f] * inv_all;
                float vsgn = vfm / fmaxf(fabsf(vfm), NEPS);
                ldV += (double)c - (double)(vsgn * nvsum[f]);
            }
        }
    }
    atomicAdd(&dbl[4 * lane + 0], la0);
    atomicAdd(&dbl[4 * lane + 1], la1);
    atomicAdd(&dbl[4 * lane + 2], la2);
    atomicAdd(&dbl[4 * lane + 3], la3);
    if (lane == 0) {
        atomicAdd(&dbl[256], lv);
        atomicAdd(&dbl[IDX_TRACE], ltr);
        atomicAdd(&dbl[IDX_VCNT], lvc);
        atomicAdd(&dbl[IDX_DEVS], ldS);
        atomicAdd(&dbl[IDX_DEVV], ldV);
    }
}

// ---------------- final combine (R10-exact) ----------------
__global__ __launch_bounds__(64) void k_final(const double* __restrict__ dbl,
                                              float* __restrict__ out) {
    if (threadIdx.x == 0 && blockIdx.x == 0) {
        double s2 = 0;
        for (int d = 0; d < 257; ++d) s2 += dbl[d] * dbl[d];
        double off = s2 - dbl[IDX_TRACE];
        double inter = off / ((double)NF * NF - NF + 1e-6);
        double vc = fmax(dbl[IDX_VCNT], 1.0);
        double total = dbl[IDX_DEVS] / vc + dbl[IDX_DEVV] / vc + 0.2 * inter;
        out[0] = (float)(0.03 * 0.05 * total);
    }
}

extern "C" void kernel_launch(void* const* d_in, const int* in_sizes, int n_in,
                              void* d_out, int out_size, void* d_ws, size_t ws_size,
                              hipStream_t stream) {
    const float* scalar_short = (const float*)d_in[0];
    const float* vector_short = (const float*)d_in[2];
    const int* fragment_ids = (const int*)d_in[4];
    const float* ln_gamma = (const float*)d_in[5];
    const float* ln_beta = (const float*)d_in[6];
    const float* W1 = (const float*)d_in[7];
    const float* b1 = (const float*)d_in[8];
    const float* Wv = (const float*)d_in[9];
    float* out = (float*)d_out;

    char* ws = (char*)d_ws;
    int* cnt = (int*)(ws + OFF_CNT);
    float* vsum = (float*)(ws + OFF_VSUM);
    float* vfsum = (float*)(ws + OFF_VFSUM);
    float* nvsum = (float*)(ws + OFF_NVSUM);
    int* fill = (int*)(ws + OFF_FILL);
    double* dbl = (double*)(ws + OFF_DBL);
    float* ssum = (float*)(ws + OFF_SSUM);
    float* nsum = (float*)(ws + OFF_NSUM);
    int* offs = (int*)(ws + OFF_OFFS);
    float* svec = (float*)(ws + OFF_SVEC);
    float* c0 = (float*)(ws + OFF_C0);
    float* w0 = (float*)(ws + OFF_W0);
    unsigned short* Gbf = (unsigned short*)(ws + OFF_GBF);
    int* order = (int*)(ws + OFF_ORDER);

    k_zero<<<2069, 256, 0, stream>>>((float4*)ws);   // [0, 8474624) exactly
    k_prep<<<HD + 1, 256, 0, stream>>>(W1, ln_gamma, ln_beta, b1, Wv, Gbf, svec, c0, w0);
    k_hist<<<NA / 256, 256, 0, stream>>>(fragment_ids, cnt);
    k_scan<<<1, 256, 0, stream>>>(cnt, offs);
    k_scatter<<<NA / 256, 256, 0, stream>>>(fragment_ids, offs, fill, order);
    k_gemm<<<NA / 64, 256, 0, stream>>>(scalar_short, Gbf, svec, c0,
                                        vector_short, w0, order, fragment_ids,
                                        offs, cnt, vsum, vfsum, nvsum, ssum, nsum);
    k_frag<<<64, 256, 0, stream>>>(ssum, nsum, cnt, vsum, vfsum, nvsum, dbl);
    k_final<<<1, 64, 0, stream>>>(dbl, out);
}

// Round 14
// 226.705 us; speedup vs baseline: 1.6677x; 1.2143x over previous
//
#include <hip/hip_runtime.h>
#include <hip/hip_bf16.h>
#include <stdint.h>

#define NA 131072
#define HD 256
#define NF 4096
#define MINFRAG 3
#define LN_EPS 1e-5f
#define NEPS 1e-12f

// ---- workspace layout (bytes) ----
// zeroed region [0, ZERO_BYTES) via k_prep (fused zero, 2069 blocks)
#define OFF_CNT    0ull          // NF i32
#define OFF_VSUM   16384ull      // NF f32
#define OFF_VFSUM  32768ull      // NF f32
#define OFF_NVSUM  49152ull      // NF f32
#define OFF_FILL   65536ull      // NF i32
#define OFF_DBL    81920ull      // unused (layout keep)
#define OFF_SSUM   86016ull      // NF*HD f32 = 4194304
#define OFF_NSUM   4280320ull    // NF*HD f32 = 4194304
#define ZERO_BYTES 8474624ull    // = 529664 float4 = 2069*256
// non-zeroed
#define OFF_OFFS   8474624ull    // NF i32
#define OFF_SVEC   8491008ull    // HD f32
#define OFF_C0     8492032ull    // HD f32
#define OFF_W0     8493056ull    // 1 f32
#define OFF_GBF    8493568ull    // HD*HD bf16 = 131072
#define OFF_ORDER  8624640ull    // NA i32 = 524288
#define OFF_PART   9150464ull    // FRAGB * PSTRIDE doubles
// total: 9,691,136 bytes

#define IDX_TRACE 257
#define IDX_DEVS  258
#define IDX_DEVV  259
#define IDX_VCNT  260
#define FRAGB 256
#define PSTRIDE 264

typedef __attribute__((ext_vector_type(8))) short short8;
typedef __attribute__((ext_vector_type(4))) float f32x4;
union F4S8 { float4 f; short8 s; };
union BFU { __hip_bfloat16 b; unsigned short u; };

__device__ __forceinline__ unsigned short f2b(float x) {
    BFU t; t.b = __float2bfloat16(x); return t.u;
}
__device__ __forceinline__ float b2f(unsigned short u) {
    return __uint_as_float(((uint32_t)u) << 16);
}
// fast silu: native v_exp + v_rcp (rel err ~1e-7, error budget ~1e-2)
__device__ __forceinline__ float silu_f(float x) {
    return x * __builtin_amdgcn_rcpf(1.f + __expf(-x));
}

// ---------------- prep (+ fused workspace zero), 2069 blocks ---------------
__global__ __launch_bounds__(256) void k_prep(
    const float* __restrict__ W1, const float* __restrict__ gamma,
    const float* __restrict__ beta, const float* __restrict__ b1,
    const float* __restrict__ Wv,
    unsigned short* __restrict__ Gbf, float* __restrict__ svec,
    float* __restrict__ c0, float* __restrict__ w0, float4* __restrict__ z) {
    __shared__ float red[8];
    int o = blockIdx.x;       // 2069 blocks
    int t = threadIdx.x;
    {   // zero [0, ZERO_BYTES): 2069*256 float4 exactly
        float4 zv = {0.f, 0.f, 0.f, 0.f};
        z[o * 256 + t] = zv;
    }
    if (o < HD) {
        float w = W1[(size_t)o * HD + t];
        unsigned short gb = f2b(w * gamma[t]);
        Gbf[(size_t)o * HD + t] = gb;
        float sp = b2f(gb);
        float cp = w * beta[t];
#pragma unroll
        for (int m = 32; m; m >>= 1) { sp += __shfl_xor(sp, m, 64); cp += __shfl_xor(cp, m, 64); }
        int wv = t >> 6;
        if ((t & 63) == 0) { red[wv] = sp; red[4 + wv] = cp; }
        __syncthreads();
        if (t == 0) {
            svec[o] = red[0] + red[1] + red[2] + red[3];
            c0[o]   = red[4] + red[5] + red[6] + red[7] + b1[o];
        }
    } else if (o == HD) {
        float v = Wv[t];
#pragma unroll
        for (int m = 32; m; m >>= 1) v += __shfl_xor(v, m, 64);
        int wv = t >> 6;
        if ((t & 63) == 0) red[wv] = v;
        __syncthreads();
        if (t == 0) w0[0] = red[0] + red[1] + red[2] + red[3];
    }
}

// ---------------- stats: contiguous pattern, 2-atom ILP (R10-exact) --------
__global__ __launch_bounds__(256) void k_stats(
    const float* __restrict__ vs, const int* __restrict__ fid,
    const float* __restrict__ w0p,
    int* __restrict__ cnt, float* __restrict__ vsum,
    float* __restrict__ vfsum, float* __restrict__ nvsum) {
    int gwave = (blockIdx.x * blockDim.x + threadIdx.x) >> 6;
    int lane = threadIdx.x & 63;
    int nw = (gridDim.x * blockDim.x) >> 6;
    float w0 = w0p[0];
    for (int i0 = gwave * 2; i0 < NA; i0 += nw * 2) {
        const float* ba = vs + (size_t)i0 * 3 * HD;
        const float* bb = vs + (size_t)(i0 + 1) * 3 * HD;
        float4 a0 = ((const float4*)(ba))[lane];
        float4 a1 = ((const float4*)(ba + HD))[lane];
        float4 a2 = ((const float4*)(ba + 2 * HD))[lane];
        float4 b0 = ((const float4*)(bb))[lane];
        float4 b1 = ((const float4*)(bb + HD))[lane];
        float4 b2 = ((const float4*)(bb + 2 * HD))[lane];
        float qa0 = a0.x * a0.x + a0.y * a0.y + a0.z * a0.z + a0.w * a0.w;
        float qa1 = a1.x * a1.x + a1.y * a1.y + a1.z * a1.z + a1.w * a1.w;
        float qa2 = a2.x * a2.x + a2.y * a2.y + a2.z * a2.z + a2.w * a2.w;
        float qb0 = b0.x * b0.x + b0.y * b0.y + b0.z * b0.z + b0.w * b0.w;
        float qb1 = b1.x * b1.x + b1.y * b1.y + b1.z * b1.z + b1.w * b1.w;
        float qb2 = b2.x * b2.x + b2.y * b2.y + b2.z * b2.z + b2.w * b2.w;
#pragma unroll
        for (int m = 32; m; m >>= 1) {   // six independent chains, interleaved
            qa0 += __shfl_xor(qa0, m, 64);
            qa1 += __shfl_xor(qa1, m, 64);
            qa2 += __shfl_xor(qa2, m, 64);
            qb0 += __shfl_xor(qb0, m, 64);
            qb1 += __shfl_xor(qb1, m, 64);
            qb2 += __shfl_xor(qb2, m, 64);
        }
        if (lane == 0) {
            float vma = (sqrtf(qa0) + sqrtf(qa1) + sqrtf(qa2)) * (1.f / 3.f);
            float vmb = (sqrtf(qb0) + sqrtf(qb1) + sqrtf(qb2)) * (1.f / 3.f);
            float vfa = silu_f(vma * w0);
            float vfb = silu_f(vmb * w0);
            float nva = vfa / fmaxf(fabsf(vfa), NEPS);
            float nvb = vfb / fmaxf(fabsf(vfb), NEPS);
            int fa = fid[i0], fb = fid[i0 + 1];
            atomicAdd(&cnt[fa], 1);
            atomicAdd(&vsum[fa], vma);
            atomicAdd(&vfsum[fa], vfa);
            atomicAdd(&nvsum[fa], nva);
            atomicAdd(&cnt[fb], 1);
            atomicAdd(&vsum[fb], vmb);
            atomicAdd(&vfsum[fb], vfb);
            atomicAdd(&nvsum[fb], nvb);
        }
    }
}

// ---------------- scan ----------------
__global__ __launch_bounds__(256) void k_scan(const int* __restrict__ cnt,
                                              int* __restrict__ offs) {
    __shared__ int wsum[4];
    int t = threadIdx.x;
    int base = t * 16;
    int c[16];
    int tot = 0;
#pragma unroll
    for (int j = 0; j < 16; ++j) { c[j] = cnt[base + j]; tot += c[j]; }
    int lane = t & 63, w = t >> 6;
    int v = tot;
#pragma unroll
    for (int d = 1; d < 64; d <<= 1) {
        int o = __shfl_up(v, d, 64);
        if (lane >= d) v += o;
    }
    if (lane == 63) wsum[w] = v;
    __syncthreads();
    int wbase = 0;
    for (int i = 0; i < w; ++i) wbase += wsum[i];
    int run = wbase + v - tot;
#pragma unroll
    for (int j = 0; j < 16; ++j) { offs[base + j] = run; run += c[j]; }
}

// ---------------- scatter ----------------
__global__ __launch_bounds__(256) void k_scatter(
    const int* __restrict__ fid, const int* __restrict__ offs,
    int* __restrict__ fill, int* __restrict__ order) {
    int i = blockIdx.x * blockDim.x + threadIdx.x;
    if (i < NA) {
        int f = fid[i];
        int p = atomicAdd(&fill[f], 1);
        order[offs[f] + p] = i;
    }
}

// ---- GEMM: single A-tile stage, B direct from L2 (R10-exact) ----
__global__ __launch_bounds__(256) void k_gemm(
    const float* __restrict__ A, const unsigned short* __restrict__ Gbf,
    const float* __restrict__ svec, const float* __restrict__ c0,
    const int* __restrict__ order, const int* __restrict__ fid,
    const int* __restrict__ offs, const int* __restrict__ cnt,
    float* __restrict__ ssum, float* __restrict__ nsum) {
    __shared__ float4 As16[64 * 32];    // 32 KB: full A tile bf16, xor-swizzled
    __shared__ float muS[64], rsS[64], rnS[64];
    __shared__ float sqL[64][4];
    __shared__ int ridS[64], fragS[64];

    int tid = threadIdx.x;
    int lane = tid & 63, wid = tid >> 6;
    int r0 = blockIdx.x * 64;
    int rowT = tid >> 4;   // 0..15
    int c4 = tid & 15;

    if (tid < 64) {
        int gi = order[r0 + tid];
        ridS[tid] = gi;
        fragS[tid] = fid[gi];
    }
    __syncthreads();
    int rid[4];
#pragma unroll
    for (int p = 0; p < 4; ++p) rid[p] = ridS[16 * p + rowT];

    // ---- stage the WHOLE A tile: 16 loads/thread, one latency exposure ----
    float s1p[4] = {0, 0, 0, 0}, s2p[4] = {0, 0, 0, 0};
#pragma unroll
    for (int kc = 0; kc < 4; ++kc)
#pragma unroll
        for (int p = 0; p < 4; ++p) {
            int row = 16 * p + rowT;
            float4 v = *(const float4*)(A + (size_t)rid[p] * HD + kc * 64 + c4 * 4);
            s1p[p] += v.x + v.y + v.z + v.w;
            s2p[p] += v.x * v.x + v.y * v.y + v.z * v.z + v.w * v.w;
            ushort4 pk;
            pk.x = f2b(v.x); pk.y = f2b(v.y); pk.z = f2b(v.z); pk.w = f2b(v.w);
            int slot = row * 32 + kc * 8 + ((c4 >> 1) ^ (row & 7));
            ((ushort4*)&As16[slot])[c4 & 1] = pk;
        }
    // LN row stats (16-lane groups)
#pragma unroll
    for (int p = 0; p < 4; ++p) {
        float s1 = s1p[p], s2 = s2p[p];
#pragma unroll
        for (int m = 1; m < 16; m <<= 1) {
            s1 += __shfl_xor(s1, m, 64);
            s2 += __shfl_xor(s2, m, 64);
        }
        if (c4 == 0) {
            int row = 16 * p + rowT;
            float mu_ = s1 * (1.f / HD);
            float var = s2 * (1.f / HD) - mu_ * mu_;
            muS[row] = mu_;
            rsS[row] = rsqrtf(var + LN_EPS);
        }
    }
    __syncthreads();   // A tile + muS ready

    // ---- MFMA phase: B fragments straight from L2-resident Gbf ----
    int lg = lane >> 4;
    const unsigned short* bp[4];
#pragma unroll
    for (int ni = 0; ni < 4; ++ni)
        bp[ni] = Gbf + (size_t)(wid * 64 + ni * 16 + (lane & 15)) * HD + lg * 8;

    f32x4 acc[4][4] = {};
#pragma unroll
    for (int kc = 0; kc < 4; ++kc) {
        short8 bfr[2][4];
#pragma unroll
        for (int kk = 0; kk < 2; ++kk)
#pragma unroll
            for (int ni = 0; ni < 4; ++ni)
                bfr[kk][ni] = *(const short8*)(bp[ni] + kc * 64 + kk * 32);
#pragma unroll
        for (int kk = 0; kk < 2; ++kk) {
            int jp = kk * 4 + lg;
            short8 a[4];
#pragma unroll
            for (int mi = 0; mi < 4; ++mi) {
                int r = mi * 16 + (lane & 15);
                F4S8 t_; t_.f = As16[r * 32 + kc * 8 + (jp ^ (r & 7))];
                a[mi] = t_.s;
            }
#pragma unroll
            for (int mi = 0; mi < 4; ++mi)
#pragma unroll
                for (int ni = 0; ni < 4; ++ni)
                    acc[mi][ni] = __builtin_amdgcn_mfma_f32_16x16x32_bf16(
                        a[mi], bfr[kk][ni], acc[mi][ni], 0, 0, 0);
        }
    }
    __syncthreads();   // all waves done reading As16 -> safe to reuse as feat

    float sv[4], cv[4];
#pragma unroll
    for (int ni = 0; ni < 4; ++ni) {
        int c = wid * 64 + ni * 16 + (lane & 15);
        sv[ni] = svec[c];
        cv[ni] = c0[c];
    }
    // epilogue: affine + silu -> feat tile in LDS (reuses As16) + per-row sq
    unsigned short* featS = (unsigned short*)As16;
    float sq[4][4];
#pragma unroll
    for (int mi = 0; mi < 4; ++mi)
#pragma unroll
        for (int q = 0; q < 4; ++q) {
            int rl = mi * 16 + (lane >> 4) * 4 + q;
            float mu_ = muS[rl], rs_ = rsS[rl];
            float sqa = 0.f;
#pragma unroll
            for (int ni = 0; ni < 4; ++ni) {
                int c = wid * 64 + ni * 16 + (lane & 15);
                float pre = rs_ * (acc[mi][ni][q] - mu_ * sv[ni]) + cv[ni];
                unsigned short us = f2b(silu_f(pre));
                featS[rl * 256 + (c ^ ((rl & 7) << 2))] = us;
                float fr = b2f(us);
                sqa += fr * fr;
            }
            sq[mi][q] = sqa;
        }
#pragma unroll
    for (int mi = 0; mi < 4; ++mi)
#pragma unroll
        for (int q = 0; q < 4; ++q) {
            float s_ = sq[mi][q];
            s_ += __shfl_xor(s_, 1, 64);
            s_ += __shfl_xor(s_, 2, 64);
            s_ += __shfl_xor(s_, 4, 64);
            s_ += __shfl_xor(s_, 8, 64);
            if ((lane & 15) == 0) sqL[mi * 16 + (lane >> 4) * 4 + q][wid] = s_;
        }
    __syncthreads();
    if (tid < 64) {
        float t = sqL[tid][0] + sqL[tid][1] + sqL[tid][2] + sqL[tid][3];
        rnS[tid] = 1.f / fmaxf(sqrtf(t), NEPS);
    }
    __syncthreads();
    // fragment-segment accumulation: one column per thread, scan 64 rows
    int cc = wid * 64 + lane;
    float sAcc = 0.f, nAcc = 0.f;
    int curF = fragS[0];
    for (int row = 0; row < 64; ++row) {
        int f = fragS[row];
        if (f != curF) {
            int gs = offs[curF], n = cnt[curF];
            if (gs >= r0 && gs + n <= r0 + 64) {
                ssum[(size_t)curF * HD + cc] = sAcc;
                nsum[(size_t)curF * HD + cc] = nAcc;
            } else {
                atomicAdd(&ssum[(size_t)curF * HD + cc], sAcc);
                atomicAdd(&nsum[(size_t)curF * HD + cc], nAcc);
            }
            sAcc = 0.f; nAcc = 0.f; curF = f;
        }
        float v = b2f(featS[row * 256 + (cc ^ ((row & 7) << 2))]);
        sAcc += v;
        nAcc = fmaf(v, rnS[row], nAcc);
    }
    {
        int gs = offs[curF], n = cnt[curF];
        if (gs >= r0 && gs + n <= r0 + 64) {
            ssum[(size_t)curF * HD + cc] = sAcc;
            nsum[(size_t)curF * HD + cc] = nAcc;
        } else {
            atomicAdd(&ssum[(size_t)curF * HD + cc], sAcc);
            atomicAdd(&nsum[(size_t)curF * HD + cc], nAcc);
        }
    }
}

// ---------------- fragment pass: block partials, NO global atomics ---------
__global__ __launch_bounds__(256) void k_frag(
    const float* __restrict__ ssum, const float* __restrict__ nsum,
    const int* __restrict__ cnt, const float* __restrict__ vsum,
    const float* __restrict__ vfsum, const float* __restrict__ nvsum,
    double* __restrict__ partial) {
    __shared__ double lred[4][PSTRIDE];
    int tid = threadIdx.x;
    int lane = tid & 63, wid = tid >> 6;
    int gwave = blockIdx.x * 4 + wid;
    const int nw = FRAGB * 4;

    double la0 = 0, la1 = 0, la2 = 0, la3 = 0;
    double lv = 0, ltr = 0, lvc = 0, ldS = 0, ldV = 0;

    for (int f = gwave; f < NF; f += nw) {
        float4 s = ((const float4*)(ssum + (size_t)f * HD))[lane];
        float4 nn = ((const float4*)(nsum + (size_t)f * HD))[lane];
        int c = cnt[f];
        float ssq = s.x * s.x + s.y * s.y + s.z * s.z + s.w * s.w;
        float dsn = nn.x * s.x + nn.y * s.y + nn.z * s.z + nn.w * s.w;
#pragma unroll
        for (int m = 32; m; m >>= 1) {
            ssq += __shfl_xor(ssq, m, 64);
            dsn += __shfl_xor(dsn, m, 64);
        }
        float inv_all = 1.f / fmaxf((float)c, 1.f);
        float m0 = s.x * inv_all, m1 = s.y * inv_all, m2 = s.z * inv_all, m3 = s.w * inv_all;
        float ssq_mean = ssq * inv_all * inv_all;
        float vfr = vsum[f] * inv_all;
        float nrm2 = ssq_mean + vfr * vfr;
        float inv = 1.f / fmaxf(sqrtf(nrm2), NEPS);
        la0 += (double)(m0 * inv);
        la1 += (double)(m1 * inv);
        la2 += (double)(m2 * inv);
        la3 += (double)(m3 * inv);
        if (lane == 0) {
            lv += (double)(vfr * inv);
            ltr += (double)(nrm2 * inv * inv);
            if (c >= MINFRAG) {
                lvc += (double)c;
                float denom = fmaxf(sqrtf(ssq), NEPS);
                ldS += (double)c - (double)(dsn / denom);
                float vfm = vfsum[f] * inv_all;
                float vsgn = vfm / fmaxf(fabsf(vfm), NEPS);
                ldV += (double)c - (double)(vsgn * nvsum[f]);
            }
        }
    }
    lred[wid][4 * lane + 0] = la0;
    lred[wid][4 * lane + 1] = la1;
    lred[wid][4 * lane + 2] = la2;
    lred[wid][4 * lane + 3] = la3;
    if (lane == 0) {
        lred[wid][256] = lv;
        lred[wid][IDX_TRACE] = ltr;
        lred[wid][IDX_DEVS] = ldS;
        lred[wid][IDX_DEVV] = ldV;
        lred[wid][IDX_VCNT] = lvc;
    }
    __syncthreads();
    for (int idx = tid; idx < 261; idx += 256)   // FIX: covers 256..260 too
        partial[(size_t)blockIdx.x * PSTRIDE + idx] =
            lred[0][idx] + lred[1][idx] + lred[2][idx] + lred[3][idx];
}

// ---------------- final: sum block partials + combine ----------------
__global__ __launch_bounds__(256) void k_final(const double* __restrict__ partial,
                                               float* __restrict__ out) {
    __shared__ double fin[PSTRIDE];
    int t = threadIdx.x;
    for (int idx = t; idx < 261; idx += 256) {
        double s = 0;
        for (int b = 0; b < FRAGB; ++b) s += partial[(size_t)b * PSTRIDE + idx];
        fin[idx] = s;
    }
    __syncthreads();
    if (t == 0) {
        double s2 = 0;
        for (int d = 0; d < 257; ++d) s2 += fin[d] * fin[d];
        double off = s2 - fin[IDX_TRACE];
        double inter = off / ((double)NF * NF - NF + 1e-6);
        double vc = fmax(fin[IDX_VCNT], 1.0);
        double total = fin[IDX_DEVS] / vc + fin[IDX_DEVV] / vc + 0.2 * inter;
        out[0] = (float)(0.03 * 0.05 * total);
    }
}

extern "C" void kernel_launch(void* const* d_in, const int* in_sizes, int n_in,
                              void* d_out, int out_size, void* d_ws, size_t ws_size,
                              hipStream_t stream) {
    const float* scalar_short = (const float*)d_in[0];
    const float* vector_short = (const float*)d_in[2];
    const int* fragment_ids = (const int*)d_in[4];
    const float* ln_gamma = (const float*)d_in[5];
    const float* ln_beta = (const float*)d_in[6];
    const float* W1 = (const float*)d_in[7];
    const float* b1 = (const float*)d_in[8];
    const float* Wv = (const float*)d_in[9];
    float* out = (float*)d_out;

    char* ws = (char*)d_ws;
    int* cnt = (int*)(ws + OFF_CNT);
    float* vsum = (float*)(ws + OFF_VSUM);
    float* vfsum = (float*)(ws + OFF_VFSUM);
    float* nvsum = (float*)(ws + OFF_NVSUM);
    int* fill = (int*)(ws + OFF_FILL);
    float* ssum = (float*)(ws + OFF_SSUM);
    float* nsum = (float*)(ws + OFF_NSUM);
    int* offs = (int*)(ws + OFF_OFFS);
    float* svec = (float*)(ws + OFF_SVEC);
    float* c0 = (float*)(ws + OFF_C0);
    float* w0 = (float*)(ws + OFF_W0);
    unsigned short* Gbf = (unsigned short*)(ws + OFF_GBF);
    int* order = (int*)(ws + OFF_ORDER);
    double* partial = (double*)(ws + OFF_PART);

    k_prep<<<2069, 256, 0, stream>>>(W1, ln_gamma, ln_beta, b1, Wv, Gbf, svec,
                                     c0, w0, (float4*)ws);
    k_stats<<<2048, 256, 0, stream>>>(vector_short, fragment_ids, w0, cnt, vsum, vfsum, nvsum);
    k_scan<<<1, 256, 0, stream>>>(cnt, offs);
    k_scatter<<<NA / 256, 256, 0, stream>>>(fragment_ids, offs, fill, order);
    k_gemm<<<NA / 64, 256, 0, stream>>>(scalar_short, Gbf, svec, c0, order,
                                        fragment_ids, offs, cnt, ssum, nsum);
    k_frag<<<FRAGB, 256, 0, stream>>>(ssum, nsum, cnt, vsum, vfsum, nvsum, partial);
    k_final<<<1, 256, 0, stream>>>(partial, out);
}

// Round 15
// 224.937 us; speedup vs baseline: 1.6809x; 1.0079x over previous
//
#include <hip/hip_runtime.h>
#include <hip/hip_bf16.h>
#include <stdint.h>

#define NA 131072
#define HD 256
#define NF 4096
#define MINFRAG 3
#define LN_EPS 1e-5f
#define NEPS 1e-12f

// ---- workspace layout (bytes) ----
// zeroed region [0, ZERO_BYTES) via k_prep (fused zero, 2069 blocks)
#define OFF_CNT    0ull          // NF i32
#define OFF_VSUM   16384ull      // NF f32
#define OFF_VFSUM  32768ull      // NF f32
#define OFF_NVSUM  49152ull      // NF f32
#define OFF_FILL   65536ull      // NF i32
#define OFF_DBL    81920ull      // unused (layout keep)
#define OFF_SSUM   86016ull      // NF*HD f32 = 4194304
#define OFF_NSUM   4280320ull    // NF*HD f32 = 4194304
#define ZERO_BYTES 8474624ull    // = 529664 float4 = 2069*256
// non-zeroed
#define OFF_OFFS   8474624ull    // NF i32
#define OFF_SVEC   8491008ull    // HD f32
#define OFF_C0     8492032ull    // HD f32
#define OFF_W0     8493056ull    // 1 f32
#define OFF_GBF    8493568ull    // HD*HD bf16 = 131072
#define OFF_ORDER  8624640ull    // NA i32 = 524288
#define OFF_PART   9150464ull    // FRAGB * PSTRIDE doubles
// total: 9,691,136 bytes

#define IDX_TRACE 257
#define IDX_DEVS  258
#define IDX_DEVV  259
#define IDX_VCNT  260
#define FRAGB 256
#define PSTRIDE 264

typedef __attribute__((ext_vector_type(8))) short short8;
typedef __attribute__((ext_vector_type(4))) float f32x4;
union F4S8 { float4 f; short8 s; };
union BFU { __hip_bfloat16 b; unsigned short u; };

__device__ __forceinline__ unsigned short f2b(float x) {
    BFU t; t.b = __float2bfloat16(x); return t.u;
}
__device__ __forceinline__ float b2f(unsigned short u) {
    return __uint_as_float(((uint32_t)u) << 16);
}
// fast silu: native v_exp + v_rcp (rel err ~1e-7, error budget ~1e-2)
__device__ __forceinline__ float silu_f(float x) {
    return x * __builtin_amdgcn_rcpf(1.f + __expf(-x));
}

// ---------------- prep (+ fused workspace zero), 2069 blocks ---------------
__global__ __launch_bounds__(256) void k_prep(
    const float* __restrict__ W1, const float* __restrict__ gamma,
    const float* __restrict__ beta, const float* __restrict__ b1,
    const float* __restrict__ Wv,
    unsigned short* __restrict__ Gbf, float* __restrict__ svec,
    float* __restrict__ c0, float* __restrict__ w0, float4* __restrict__ z) {
    __shared__ float red[8];
    int o = blockIdx.x;       // 2069 blocks
    int t = threadIdx.x;
    {   // zero [0, ZERO_BYTES): 2069*256 float4 exactly
        float4 zv = {0.f, 0.f, 0.f, 0.f};
        z[o * 256 + t] = zv;
    }
    if (o < HD) {
        float w = W1[(size_t)o * HD + t];
        unsigned short gb = f2b(w * gamma[t]);
        Gbf[(size_t)o * HD + t] = gb;
        float sp = b2f(gb);
        float cp = w * beta[t];
#pragma unroll
        for (int m = 32; m; m >>= 1) { sp += __shfl_xor(sp, m, 64); cp += __shfl_xor(cp, m, 64); }
        int wv = t >> 6;
        if ((t & 63) == 0) { red[wv] = sp; red[4 + wv] = cp; }
        __syncthreads();
        if (t == 0) {
            svec[o] = red[0] + red[1] + red[2] + red[3];
            c0[o]   = red[4] + red[5] + red[6] + red[7] + b1[o];
        }
    } else if (o == HD) {
        float v = Wv[t];
#pragma unroll
        for (int m = 32; m; m >>= 1) v += __shfl_xor(v, m, 64);
        int wv = t >> 6;
        if ((t & 63) == 0) red[wv] = v;
        __syncthreads();
        if (t == 0) w0[0] = red[0] + red[1] + red[2] + red[3];
    }
}

// ---- stats: 16-lane groups (4 atoms/wave-iter), contiguous 256B segments,
//      4-step reduce x3 interleaved, tail work on 4 lanes ----
__global__ __launch_bounds__(256) void k_stats(
    const float* __restrict__ vs, const int* __restrict__ fid,
    const float* __restrict__ w0p,
    int* __restrict__ cnt, float* __restrict__ vsum,
    float* __restrict__ vfsum, float* __restrict__ nvsum) {
    int gwave = (blockIdx.x * blockDim.x + threadIdx.x) >> 6;
    int lane = threadIdx.x & 63;
    int nw = (gridDim.x * blockDim.x) >> 6;
    int g = lane >> 4, sl = lane & 15;
    float w0 = w0p[0];
    for (int i0 = gwave * 4; i0 < NA; i0 += nw * 4) {
        int i = i0 + g;
        const float* vb = vs + (size_t)i * 3 * HD;
        float q0 = 0.f, q1 = 0.f, q2 = 0.f;
#pragma unroll
        for (int j = 0; j < 4; ++j) {
            // lanes sl=0..15 read contiguous 256B per instruction
            float4 a = ((const float4*)(vb))[j * 16 + sl];
            float4 b = ((const float4*)(vb + HD))[j * 16 + sl];
            float4 c = ((const float4*)(vb + 2 * HD))[j * 16 + sl];
            q0 += a.x * a.x + a.y * a.y + a.z * a.z + a.w * a.w;
            q1 += b.x * b.x + b.y * b.y + b.z * b.z + b.w * b.w;
            q2 += c.x * c.x + c.y * c.y + c.z * c.z + c.w * c.w;
        }
#pragma unroll
        for (int m = 1; m < 16; m <<= 1) {   // stays within 16-lane group
            q0 += __shfl_xor(q0, m, 64);
            q1 += __shfl_xor(q1, m, 64);
            q2 += __shfl_xor(q2, m, 64);
        }
        if (sl == 0) {
            float vm = (sqrtf(q0) + sqrtf(q1) + sqrtf(q2)) * (1.f / 3.f);
            float vf = silu_f(vm * w0);
            float nv = vf / fmaxf(fabsf(vf), NEPS);
            int f = fid[i];
            atomicAdd(&cnt[f], 1);
            atomicAdd(&vsum[f], vm);
            atomicAdd(&vfsum[f], vf);
            atomicAdd(&nvsum[f], nv);
        }
    }
}

// ---------------- scan ----------------
__global__ __launch_bounds__(256) void k_scan(const int* __restrict__ cnt,
                                              int* __restrict__ offs) {
    __shared__ int wsum[4];
    int t = threadIdx.x;
    int base = t * 16;
    int c[16];
    int tot = 0;
#pragma unroll
    for (int j = 0; j < 16; ++j) { c[j] = cnt[base + j]; tot += c[j]; }
    int lane = t & 63, w = t >> 6;
    int v = tot;
#pragma unroll
    for (int d = 1; d < 64; d <<= 1) {
        int o = __shfl_up(v, d, 64);
        if (lane >= d) v += o;
    }
    if (lane == 63) wsum[w] = v;
    __syncthreads();
    int wbase = 0;
    for (int i = 0; i < w; ++i) wbase += wsum[i];
    int run = wbase + v - tot;
#pragma unroll
    for (int j = 0; j < 16; ++j) { offs[base + j] = run; run += c[j]; }
}

// ---------------- scatter ----------------
__global__ __launch_bounds__(256) void k_scatter(
    const int* __restrict__ fid, const int* __restrict__ offs,
    int* __restrict__ fill, int* __restrict__ order) {
    int i = blockIdx.x * blockDim.x + threadIdx.x;
    if (i < NA) {
        int f = fid[i];
        int p = atomicAdd(&fill[f], 1);
        order[offs[f] + p] = i;
    }
}

// ---- GEMM: single A-tile stage, B direct from L2 (R10-exact) ----
__global__ __launch_bounds__(256) void k_gemm(
    const float* __restrict__ A, const unsigned short* __restrict__ Gbf,
    const float* __restrict__ svec, const float* __restrict__ c0,
    const int* __restrict__ order, const int* __restrict__ fid,
    const int* __restrict__ offs, const int* __restrict__ cnt,
    float* __restrict__ ssum, float* __restrict__ nsum) {
    __shared__ float4 As16[64 * 32];    // 32 KB: full A tile bf16, xor-swizzled
    __shared__ float muS[64], rsS[64], rnS[64];
    __shared__ float sqL[64][4];
    __shared__ int ridS[64], fragS[64];

    int tid = threadIdx.x;
    int lane = tid & 63, wid = tid >> 6;
    int r0 = blockIdx.x * 64;
    int rowT = tid >> 4;   // 0..15
    int c4 = tid & 15;

    if (tid < 64) {
        int gi = order[r0 + tid];
        ridS[tid] = gi;
        fragS[tid] = fid[gi];
    }
    __syncthreads();
    int rid[4];
#pragma unroll
    for (int p = 0; p < 4; ++p) rid[p] = ridS[16 * p + rowT];

    // ---- stage the WHOLE A tile: 16 loads/thread, one latency exposure ----
    float s1p[4] = {0, 0, 0, 0}, s2p[4] = {0, 0, 0, 0};
#pragma unroll
    for (int kc = 0; kc < 4; ++kc)
#pragma unroll
        for (int p = 0; p < 4; ++p) {
            int row = 16 * p + rowT;
            float4 v = *(const float4*)(A + (size_t)rid[p] * HD + kc * 64 + c4 * 4);
            s1p[p] += v.x + v.y + v.z + v.w;
            s2p[p] += v.x * v.x + v.y * v.y + v.z * v.z + v.w * v.w;
            ushort4 pk;
            pk.x = f2b(v.x); pk.y = f2b(v.y); pk.z = f2b(v.z); pk.w = f2b(v.w);
            int slot = row * 32 + kc * 8 + ((c4 >> 1) ^ (row & 7));
            ((ushort4*)&As16[slot])[c4 & 1] = pk;
        }
    // LN row stats (16-lane groups)
#pragma unroll
    for (int p = 0; p < 4; ++p) {
        float s1 = s1p[p], s2 = s2p[p];
#pragma unroll
        for (int m = 1; m < 16; m <<= 1) {
            s1 += __shfl_xor(s1, m, 64);
            s2 += __shfl_xor(s2, m, 64);
        }
        if (c4 == 0) {
            int row = 16 * p + rowT;
            float mu_ = s1 * (1.f / HD);
            float var = s2 * (1.f / HD) - mu_ * mu_;
            muS[row] = mu_;
            rsS[row] = rsqrtf(var + LN_EPS);
        }
    }
    __syncthreads();   // A tile + muS ready

    // ---- MFMA phase: B fragments straight from L2-resident Gbf ----
    int lg = lane >> 4;
    const unsigned short* bp[4];
#pragma unroll
    for (int ni = 0; ni < 4; ++ni)
        bp[ni] = Gbf + (size_t)(wid * 64 + ni * 16 + (lane & 15)) * HD + lg * 8;

    f32x4 acc[4][4] = {};
#pragma unroll
    for (int kc = 0; kc < 4; ++kc) {
        short8 bfr[2][4];
#pragma unroll
        for (int kk = 0; kk < 2; ++kk)
#pragma unroll
            for (int ni = 0; ni < 4; ++ni)
                bfr[kk][ni] = *(const short8*)(bp[ni] + kc * 64 + kk * 32);
#pragma unroll
        for (int kk = 0; kk < 2; ++kk) {
            int jp = kk * 4 + lg;
            short8 a[4];
#pragma unroll
            for (int mi = 0; mi < 4; ++mi) {
                int r = mi * 16 + (lane & 15);
                F4S8 t_; t_.f = As16[r * 32 + kc * 8 + (jp ^ (r & 7))];
                a[mi] = t_.s;
            }
#pragma unroll
            for (int mi = 0; mi < 4; ++mi)
#pragma unroll
                for (int ni = 0; ni < 4; ++ni)
                    acc[mi][ni] = __builtin_amdgcn_mfma_f32_16x16x32_bf16(
                        a[mi], bfr[kk][ni], acc[mi][ni], 0, 0, 0);
        }
    }
    __syncthreads();   // all waves done reading As16 -> safe to reuse as feat

    float sv[4], cv[4];
#pragma unroll
    for (int ni = 0; ni < 4; ++ni) {
        int c = wid * 64 + ni * 16 + (lane & 15);
        sv[ni] = svec[c];
        cv[ni] = c0[c];
    }
    // epilogue: affine + silu -> feat tile in LDS (reuses As16) + per-row sq
    unsigned short* featS = (unsigned short*)As16;
    float sq[4][4];
#pragma unroll
    for (int mi = 0; mi < 4; ++mi)
#pragma unroll
        for (int q = 0; q < 4; ++q) {
            int rl = mi * 16 + (lane >> 4) * 4 + q;
            float mu_ = muS[rl], rs_ = rsS[rl];
            float sqa = 0.f;
#pragma unroll
            for (int ni = 0; ni < 4; ++ni) {
                int c = wid * 64 + ni * 16 + (lane & 15);
                float pre = rs_ * (acc[mi][ni][q] - mu_ * sv[ni]) + cv[ni];
                unsigned short us = f2b(silu_f(pre));
                featS[rl * 256 + (c ^ ((rl & 7) << 2))] = us;
                float fr = b2f(us);
                sqa += fr * fr;
            }
            sq[mi][q] = sqa;
        }
#pragma unroll
    for (int mi = 0; mi < 4; ++mi)
#pragma unroll
        for (int q = 0; q < 4; ++q) {
            float s_ = sq[mi][q];
            s_ += __shfl_xor(s_, 1, 64);
            s_ += __shfl_xor(s_, 2, 64);
            s_ += __shfl_xor(s_, 4, 64);
            s_ += __shfl_xor(s_, 8, 64);
            if ((lane & 15) == 0) sqL[mi * 16 + (lane >> 4) * 4 + q][wid] = s_;
        }
    __syncthreads();
    if (tid < 64) {
        float t = sqL[tid][0] + sqL[tid][1] + sqL[tid][2] + sqL[tid][3];
        rnS[tid] = 1.f / fmaxf(sqrtf(t), NEPS);
    }
    __syncthreads();
    // fragment-segment accumulation: one column per thread, scan 64 rows
    int cc = wid * 64 + lane;
    float sAcc = 0.f, nAcc = 0.f;
    int curF = fragS[0];
    for (int row = 0; row < 64; ++row) {
        int f = fragS[row];
        if (f != curF) {
            int gs = offs[curF], n = cnt[curF];
            if (gs >= r0 && gs + n <= r0 + 64) {
                ssum[(size_t)curF * HD + cc] = sAcc;
                nsum[(size_t)curF * HD + cc] = nAcc;
            } else {
                atomicAdd(&ssum[(size_t)curF * HD + cc], sAcc);
                atomicAdd(&nsum[(size_t)curF * HD + cc], nAcc);
            }
            sAcc = 0.f; nAcc = 0.f; curF = f;
        }
        float v = b2f(featS[row * 256 + (cc ^ ((row & 7) << 2))]);
        sAcc += v;
        nAcc = fmaf(v, rnS[row], nAcc);
    }
    {
        int gs = offs[curF], n = cnt[curF];
        if (gs >= r0 && gs + n <= r0 + 64) {
            ssum[(size_t)curF * HD + cc] = sAcc;
            nsum[(size_t)curF * HD + cc] = nAcc;
        } else {
            atomicAdd(&ssum[(size_t)curF * HD + cc], sAcc);
            atomicAdd(&nsum[(size_t)curF * HD + cc], nAcc);
        }
    }
}

// ---------------- fragment pass: block partials, NO global atomics ---------
__global__ __launch_bounds__(256) void k_frag(
    const float* __restrict__ ssum, const float* __restrict__ nsum,
    const int* __restrict__ cnt, const float* __restrict__ vsum,
    const float* __restrict__ vfsum, const float* __restrict__ nvsum,
    double* __restrict__ partial) {
    __shared__ double lred[4][PSTRIDE];
    int tid = threadIdx.x;
    int lane = tid & 63, wid = tid >> 6;
    int gwave = blockIdx.x * 4 + wid;
    const int nw = FRAGB * 4;

    double la0 = 0, la1 = 0, la2 = 0, la3 = 0;
    double lv = 0, ltr = 0, lvc = 0, ldS = 0, ldV = 0;

    for (int f = gwave; f < NF; f += nw) {
        float4 s = ((const float4*)(ssum + (size_t)f * HD))[lane];
        float4 nn = ((const float4*)(nsum + (size_t)f * HD))[lane];
        int c = cnt[f];
        float ssq = s.x * s.x + s.y * s.y + s.z * s.z + s.w * s.w;
        float dsn = nn.x * s.x + nn.y * s.y + nn.z * s.z + nn.w * s.w;
#pragma unroll
        for (int m = 32; m; m >>= 1) {
            ssq += __shfl_xor(ssq, m, 64);
            dsn += __shfl_xor(dsn, m, 64);
        }
        float inv_all = 1.f / fmaxf((float)c, 1.f);
        float m0 = s.x * inv_all, m1 = s.y * inv_all, m2 = s.z * inv_all, m3 = s.w * inv_all;
        float ssq_mean = ssq * inv_all * inv_all;
        float vfr = vsum[f] * inv_all;
        float nrm2 = ssq_mean + vfr * vfr;
        float inv = 1.f / fmaxf(sqrtf(nrm2), NEPS);
        la0 += (double)(m0 * inv);
        la1 += (double)(m1 * inv);
        la2 += (double)(m2 * inv);
        la3 += (double)(m3 * inv);
        if (lane == 0) {
            lv += (double)(vfr * inv);
            ltr += (double)(nrm2 * inv * inv);
            if (c >= MINFRAG) {
                lvc += (double)c;
                float denom = fmaxf(sqrtf(ssq), NEPS);
                ldS += (double)c - (double)(dsn / denom);
                float vfm = vfsum[f] * inv_all;
                float vsgn = vfm / fmaxf(fabsf(vfm), NEPS);
                ldV += (double)c - (double)(vsgn * nvsum[f]);
            }
        }
    }
    lred[wid][4 * lane + 0] = la0;
    lred[wid][4 * lane + 1] = la1;
    lred[wid][4 * lane + 2] = la2;
    lred[wid][4 * lane + 3] = la3;
    if (lane == 0) {
        lred[wid][256] = lv;
        lred[wid][IDX_TRACE] = ltr;
        lred[wid][IDX_DEVS] = ldS;
        lred[wid][IDX_DEVV] = ldV;
        lred[wid][IDX_VCNT] = lvc;
    }
    __syncthreads();
    for (int idx = tid; idx < 261; idx += 256)
        partial[(size_t)blockIdx.x * PSTRIDE + idx] =
            lred[0][idx] + lred[1][idx] + lred[2][idx] + lred[3][idx];
}

// ---------------- final: sum block partials + combine ----------------
__global__ __launch_bounds__(256) void k_final(const double* __restrict__ partial,
                                               float* __restrict__ out) {
    __shared__ double fin[PSTRIDE];
    int t = threadIdx.x;
    for (int idx = t; idx < 261; idx += 256) {
        double s = 0;
        for (int b = 0; b < FRAGB; ++b) s += partial[(size_t)b * PSTRIDE + idx];
        fin[idx] = s;
    }
    __syncthreads();
    if (t == 0) {
        double s2 = 0;
        for (int d = 0; d < 257; ++d) s2 += fin[d] * fin[d];
        double off = s2 - fin[IDX_TRACE];
        double inter = off / ((double)NF * NF - NF + 1e-6);
        double vc = fmax(fin[IDX_VCNT], 1.0);
        double total = fin[IDX_DEVS] / vc + fin[IDX_DEVV] / vc + 0.2 * inter;
        out[0] = (float)(0.03 * 0.05 * total);
    }
}

extern "C" void kernel_launch(void* const* d_in, const int* in_sizes, int n_in,
                              void* d_out, int out_size, void* d_ws, size_t ws_size,
                              hipStream_t stream) {
    const float* scalar_short = (const float*)d_in[0];
    const float* vector_short = (const float*)d_in[2];
    const int* fragment_ids = (const int*)d_in[4];
    const float* ln_gamma = (const float*)d_in[5];
    const float* ln_beta = (const float*)d_in[6];
    const float* W1 = (const float*)d_in[7];
    const float* b1 = (const float*)d_in[8];
    const float* Wv = (const float*)d_in[9];
    float* out = (float*)d_out;

    char* ws = (char*)d_ws;
    int* cnt = (int*)(ws + OFF_CNT);
    float* vsum = (float*)(ws + OFF_VSUM);
    float* vfsum = (float*)(ws + OFF_VFSUM);
    float* nvsum = (float*)(ws + OFF_NVSUM);
    int* fill = (int*)(ws + OFF_FILL);
    float* ssum = (float*)(ws + OFF_SSUM);
    float* nsum = (float*)(ws + OFF_NSUM);
    int* offs = (int*)(ws + OFF_OFFS);
    float* svec = (float*)(ws + OFF_SVEC);
    float* c0 = (float*)(ws + OFF_C0);
    float* w0 = (float*)(ws + OFF_W0);
    unsigned short* Gbf = (unsigned short*)(ws + OFF_GBF);
    int* order = (int*)(ws + OFF_ORDER);
    double* partial = (double*)(ws + OFF_PART);

    k_prep<<<2069, 256, 0, stream>>>(W1, ln_gamma, ln_beta, b1, Wv, Gbf, svec,
                                     c0, w0, (float4*)ws);
    k_stats<<<2048, 256, 0, stream>>>(vector_short, fragment_ids, w0, cnt, vsum, vfsum, nvsum);
    k_scan<<<1, 256, 0, stream>>>(cnt, offs);
    k_scatter<<<NA / 256, 256, 0, stream>>>(fragment_ids, offs, fill, order);
    k_gemm<<<NA / 64, 256, 0, stream>>>(scalar_short, Gbf, svec, c0, order,
                                        fragment_ids, offs, cnt, ssum, nsum);
    k_frag<<<FRAGB, 256, 0, stream>>>(ssum, nsum, cnt, vsum, vfsum, nvsum, partial);
    k_final<<<1, 256, 0, stream>>>(partial, out);
}